// Round 5
// baseline (288.370 us; speedup 1.0000x reference)
//
#include <hip/hip_runtime.h>
#include <stdint.h>

#define D_DIM 1024
#define T_DIM 4096
#define B_DIM 4
#define M_DIM 16384
#define NX 16777216UL
#define NW 1048576UL
#define LOG8F 2.0794415416798357f
#define CHUNK_L 64
#define NCHUNK 64
#define WARM 16
#define NT 32

typedef __attribute__((ext_vector_type(4))) float f32x4;
typedef __attribute__((ext_vector_type(8))) short bf16x8;

__device__ __forceinline__ unsigned short f2bf(float f) {
    unsigned u = __float_as_uint(f);
    u += 0x7fffu + ((u >> 16) & 1u);
    return (unsigned short)(u >> 16);
}
__device__ __forceinline__ float unp_lo(unsigned p) { return __uint_as_float(p << 16); }
__device__ __forceinline__ float unp_hi(unsigned p) { return __uint_as_float(p & 0xffff0000u); }
__device__ __forceinline__ float sigm(float x) { return 1.0f / (1.0f + __expf(-x)); }

__device__ __forceinline__ void gl_lds16(const void* g, void* l) {
    __builtin_amdgcn_global_load_lds(
        (const __attribute__((address_space(1))) void*)g,
        (__attribute__((address_space(3))) void*)l, 16, 0, 0);
}

// ---------------------------------------------------------------------------
// Kernel 0: convert x, W_r, W_i, W_x  fp32 -> bf16 (4 elems/thread)
// ---------------------------------------------------------------------------
__global__ __launch_bounds__(256) void cvt_kernel(
    const float* __restrict__ x, const float* __restrict__ Wr,
    const float* __restrict__ Wi, const float* __restrict__ Wx,
    unsigned short* __restrict__ xb, unsigned short* __restrict__ wb)
{
    size_t tid = (size_t)blockIdx.x * 256 + threadIdx.x;
    size_t i = tid * 4;
    const float* src;
    unsigned short* dst;
    size_t off;
    if (i < NX) {
        src = x; dst = xb; off = i;
    } else {
        size_t j = i - NX;
        size_t w = j >> 20;           // / NW
        off = j & (NW - 1);
        src = (w == 0) ? Wr : (w == 1 ? Wi : Wx);
        dst = wb + w * NW;
    }
    float4 v = *(const float4*)(src + off);
    ushort4 o;
    o.x = f2bf(v.x); o.y = f2bf(v.y); o.z = f2bf(v.z); o.w = f2bf(v.w);
    *(ushort4*)(dst + off) = o;
}

// ---------------------------------------------------------------------------
// Kernel 1: single-pass 3-fused GEMM + gating, cross-tile REGISTER pipeline.
//   R4 post-mortem: 128m-wave tile spilled (VGPR capped 128, acc 192 ->
//   >=64 regs to scratch, ~4600 cy/tile scratch traffic, 204 us). Register
//   file, not LDS, blocks bigger tiles. Back to R1's proven geometry
//   (146 us, 88 VGPR, 0 bank conflicts) and attack R1's measured stall:
//   per tile, [8-wave ds_read burst ~960 cy, matrix idle] then [MFMA burst
//   ~930 cy, LDS idle] + sync ~800 -> 2737 cy/tile (MfmaUtil 31%).
//   Fix: double-buffer the FRAGMENT registers. At tile t the barrier now
//   publishes tile t+1 as well (vmcnt retimed: steady-state vmcnt(4) =
//   "stage(t+1) landed", 12 loads in flight from 3 staged tiles), so the
//   ds_reads for tile t+1 issue CONCURRENTLY with tile t's 24 MFMAs
//   (independent registers -> scheduler interleaves; deps resolved by
//   compiler's counted lgkmcnt). LDS pipe and matrix pipe overlap instead
//   of alternating. This is m201's phase-overlap mechanism at BK=32 --
//   the {counted-vmcnt + reg-prefetch} combo, untested in m133 (which
//   grafted reg-prefetch onto a vmcnt(0)-drain loop).
//   - 4-deep LDS kept (reads target buf (t+1)&3; stage(t+3) writes
//     (t+3)&3, always distinct; overwritten buf last read 2 barriers ago).
//   - regs: acc 96 (AGPR) + frags 2x40 + addr ~30 = ~226 <= 256 cap from
//     __launch_bounds__(512,2) -- R1 ran fine under the same cap.
//   - XOR-swizzle kept (measured 0 conflicts). setprio kept.
//   - grid map kept: bid&7 = d-tile = XCD -> W-slice L2-resident.
// ---------------------------------------------------------------------------
__global__ __launch_bounds__(512, 2) void fused_gemm(
    const unsigned short* __restrict__ xb, const unsigned short* __restrict__ wb,
    const float* __restrict__ b_r, const float* __restrict__ b_i,
    unsigned short* __restrict__ a_out, float* __restrict__ u_out)
{
    // per buffer: A[128][32] = 4096 ush (8 KB) then B[3][128][32] = 12288 ush
    __shared__ __align__(16) unsigned short lds[4][16384];   // 128 KB

    const int tid  = threadIdx.x;
    const int lane = tid & 63;
    const int wave = tid >> 6;
    const int wm = wave & 1;            // m-half (64 rows of 128)
    const int wn = wave >> 1;           // d-quarter (32 cols of 128)
    const int m0 = ((int)blockIdx.x >> 3) * 128;
    const int d0 = ((int)blockIdx.x & 7) * 128;
    const int frow = lane & 15;
    const int kgrp = lane >> 4;

    // staging: thread -> LDS slot (row=tid>>2, cg=tid&3); global source
    // col-group inverse-swizzled so swizzled ds_read returns correct data
    const int r0 = tid >> 2;            // 0..127
    const int cgs = (tid & 3) ^ ((r0 >> 1) & 3);
    const unsigned short* srcA  = xb + (size_t)(m0 + r0) * D_DIM + cgs * 8;
    const unsigned short* srcB0 = wb + (size_t)(d0 + r0) * D_DIM + cgs * 8;
    const unsigned short* srcB1 = srcB0 + NW;
    const unsigned short* srcB2 = srcB0 + 2 * NW;

    // reader offsets (ushort units, within one 16384-ush buffer), swizzled
    int offA[4], offB[3][2];
    #pragma unroll
    for (int i = 0; i < 4; i++) {
        const int row = wm * 64 + i * 16 + frow;
        offA[i] = row * 32 + ((kgrp ^ ((row >> 1) & 3)) << 3);
    }
    #pragma unroll
    for (int w = 0; w < 3; w++)
        #pragma unroll
        for (int j = 0; j < 2; j++) {
            const int row = wn * 32 + j * 16 + frow;
            offB[w][j] = (1 + w) * 4096 + row * 32 + ((kgrp ^ ((row >> 1) & 3)) << 3);
        }

    f32x4 acc[3][4][2];
    #pragma unroll
    for (int w = 0; w < 3; w++)
        #pragma unroll
        for (int i = 0; i < 4; i++)
            #pragma unroll
            for (int j = 0; j < 2; j++) acc[w][i][j] = (f32x4){0.f, 0.f, 0.f, 0.f};

    auto stage = [&](int t) {
        const int buf = t & 3;
        const int k0 = t << 5;
        gl_lds16(srcA  + k0, &lds[buf][tid * 8]);
        gl_lds16(srcB0 + k0, &lds[buf][4096 + tid * 8]);
        gl_lds16(srcB1 + k0, &lds[buf][8192 + tid * 8]);
        gl_lds16(srcB2 + k0, &lds[buf][12288 + tid * 8]);
    };

    // double-buffered fragments (explicit names -- rule 20: static indexing)
    bf16x8 af_a[4], af_b[4], bf_a[3][2], bf_b[3][2];

    stage(0); stage(1); stage(2);
    asm volatile("s_waitcnt vmcnt(8)" ::: "memory");   // stage(0) landed
    __builtin_amdgcn_s_barrier();
    asm volatile("" ::: "memory");
    #pragma unroll
    for (int i = 0; i < 4; i++) af_a[i] = *(const bf16x8*)&lds[0][offA[i]];
    #pragma unroll
    for (int w = 0; w < 3; w++)
        #pragma unroll
        for (int j = 0; j < 2; j++) bf_a[w][j] = *(const bf16x8*)&lds[0][offB[w][j]];

// STEP(T): vmcnt(VM) guarantees stage(T+1) landed (steady state: 3 tiles in
// flight, outstanding allowed = stage(T+2)'s 4 loads). Barrier publishes
// tile T+1. Then: prefetch-issue stage(T+3), ds_read tile T+1's fragments
// into the NXT bank, and run tile T's 24 MFMAs from the CUR bank -- reads
// and MFMAs are register-independent, so they interleave on the two pipes.
#define STEP(T, AFC, BFC, AFN, BFN, VM)                                       \
    {                                                                         \
        asm volatile("s_waitcnt vmcnt(" #VM ")" ::: "memory");                \
        __builtin_amdgcn_s_barrier();                                         \
        asm volatile("" ::: "memory");                                        \
        if ((T) + 3 < NT) stage((T) + 3);                                     \
        if ((T) + 1 < NT) {                                                   \
            const unsigned short* nb = lds[((T) + 1) & 3];                    \
            _Pragma("unroll")                                                 \
            for (int i = 0; i < 4; i++)                                       \
                AFN[i] = *(const bf16x8*)&nb[offA[i]];                        \
            _Pragma("unroll")                                                 \
            for (int w = 0; w < 3; w++)                                       \
                _Pragma("unroll")                                             \
                for (int j = 0; j < 2; j++)                                   \
                    BFN[w][j] = *(const bf16x8*)&nb[offB[w][j]];              \
        }                                                                     \
        __builtin_amdgcn_s_setprio(1);                                        \
        _Pragma("unroll")                                                     \
        for (int w = 0; w < 3; w++)                                           \
            _Pragma("unroll")                                                 \
            for (int i = 0; i < 4; i++)                                       \
                _Pragma("unroll")                                             \
                for (int j = 0; j < 2; j++)                                   \
                    acc[w][i][j] = __builtin_amdgcn_mfma_f32_16x16x32_bf16(   \
                        AFC[i], BFC[w][j], acc[w][i][j], 0, 0, 0);            \
        __builtin_amdgcn_s_setprio(0);                                        \
    }

    for (int t = 0; t < 28; t += 2) {
        STEP(t,     af_a, bf_a, af_b, bf_b, 4);
        STEP(t + 1, af_b, bf_b, af_a, bf_a, 4);
    }
    STEP(28, af_a, bf_a, af_b, bf_b, 4);
    STEP(29, af_b, bf_b, af_a, bf_a, 4);
    STEP(30, af_a, bf_a, af_b, bf_b, 0);   // stage(31) is the last in flight
    STEP(31, af_b, bf_b, af_a, bf_a, 0);
#undef STEP

    // Epilogue. C/D layout: col(d) = lane&15, row(m) = (lane>>4)*4 + r.
    const int mb = m0 + wm * 64 + kgrp * 4;
    const int db = d0 + wn * 32 + frow;
    #pragma unroll
    for (int j = 0; j < 2; j++) {
        const int d = db + j * 16;
        const float br = b_r[d];
        const float bi = b_i[d];
        #pragma unroll
        for (int i = 0; i < 4; i++) {
            const int m = mb + i * 16;
            #pragma unroll
            for (int r = 0; r < 4; r++) {
                const size_t idx = (size_t)(m + r) * D_DIM + d;
                float rg = sigm(acc[0][i][j][r] + br);
                // exp(-softplus(z)) == sigmoid(-z);  a in (0.11, 0.5)
                float a = sigm(-LOG8F * rg);
                a_out[idx] = f2bf(a);
                float g = sqrtf(fmaxf(1.0f - a * a, 1e-6f));
                u_out[idx] = g * sigm(acc[1][i][j][r] + bi) * acc[2][i][j][r];
            }
        }
    }
}

// ---------------------------------------------------------------------------
// Kernel 2: chunk-start h via 16-step warm-up (a <= 0.5 => decay >= 1 bit/step,
// so truncation error <= 2^-16 * |h|). 2 d-chains per thread (float2 loads).
// Must stay a separate launch: apply overwrites u in place, warm reads u.
// ---------------------------------------------------------------------------
__global__ __launch_bounds__(256) void scan_warm(
    const unsigned short* __restrict__ a, const float* __restrict__ u,
    const float* __restrict__ h0, float* __restrict__ hstart)
{
    int tid = blockIdx.x * 256 + threadIdx.x;   // (b*NCHUNK + c)*512 + d2
    int d = (tid & 511) << 1;
    int bc = tid >> 9;
    int b = bc >> 6;
    int c = bc & (NCHUNK - 1);
    float hx, hy;
    if (c == 0) {
        float2 h = *(const float2*)(h0 + b * D_DIM + d);
        hx = h.x; hy = h.y;
    } else {
        hx = 0.0f; hy = 0.0f;
        size_t base = ((size_t)b * T_DIM + (size_t)c * CHUNK_L - WARM) * D_DIM + d;
        #pragma unroll 4
        for (int t = 0; t < WARM; t++) {
            size_t idx = base + (size_t)t * D_DIM;
            unsigned ap = *(const unsigned*)(a + idx);
            float2 uv = *(const float2*)(u + idx);
            hx = unp_lo(ap) * hx + uv.x;
            hy = unp_hi(ap) * hy + uv.y;
        }
    }
    *(float2*)(hstart + bc * D_DIM + d) = make_float2(hx, hy);
}

// ---------------------------------------------------------------------------
// Kernel 3: apply — scan each chunk from hstart, overwrite u -> h in place.
// 2 d-chains per thread. Last chunk's thread also writes h_last.
// ---------------------------------------------------------------------------
__global__ __launch_bounds__(256) void scan_apply(
    const unsigned short* __restrict__ a, const float* __restrict__ hstart,
    float* __restrict__ out)
{
    int tid = blockIdx.x * 256 + threadIdx.x;
    int d = (tid & 511) << 1;
    int bc = tid >> 9;
    int b = bc >> 6;
    int c = bc & (NCHUNK - 1);
    size_t base = ((size_t)b * T_DIM + (size_t)c * CHUNK_L) * D_DIM + d;
    float2 h = *(const float2*)(hstart + bc * D_DIM + d);
    float hx = h.x, hy = h.y;
    #pragma unroll 4
    for (int t = 0; t < CHUNK_L; t++) {
        size_t idx = base + (size_t)t * D_DIM;
        unsigned ap = *(const unsigned*)(a + idx);
        float2 uv = *(const float2*)(out + idx);
        hx = unp_lo(ap) * hx + uv.x;
        hy = unp_hi(ap) * hy + uv.y;
        *(float2*)(out + idx) = make_float2(hx, hy);
    }
    if (c == NCHUNK - 1)
        *(float2*)(out + (size_t)M_DIM * D_DIM + b * D_DIM + d) = make_float2(hx, hy);
}

// ---------------------------------------------------------------------------
extern "C" void kernel_launch(void* const* d_in, const int* in_sizes, int n_in,
                              void* d_out, int out_size, void* d_ws, size_t ws_size,
                              hipStream_t stream)
{
    const float* x  = (const float*)d_in[0];
    const float* h0 = (const float*)d_in[1];
    const float* Wr = (const float*)d_in[2];
    const float* br = (const float*)d_in[3];
    const float* Wi = (const float*)d_in[4];
    const float* bi = (const float*)d_in[5];
    const float* Wx = (const float*)d_in[6];
    float* out = (float*)d_out;

    char* ws = (char*)d_ws;
    unsigned short* xb = (unsigned short*)ws;                          // 32 MB
    unsigned short* wb = (unsigned short*)(ws + 33554432);             // 6 MB
    unsigned short* a_buf = (unsigned short*)(ws + 33554432 + 6291456);// 32 MB bf16
    float* hstart = (float*)(ws + 33554432 + 6291456 + 33554432);      // 1 MB

    // 0: fp32 -> bf16 (x and the three weights)
    cvt_kernel<<<19456, 256, 0, stream>>>(x, Wr, Wi, Wx, xb, wb);
    // 1: single-pass 3-fused GEMM + gating. a(bf16) -> ws, u(fp32) -> d_out
    fused_gemm<<<1024, 512, 0, stream>>>(xb, wb, br, bi, a_buf, out);
    // 2: chunk-start h via warm-up (no sequential dependency)
    scan_warm<<<512, 256, 0, stream>>>(a_buf, out, h0, hstart);
    // 3: in-place chunk scan + h_last
    scan_apply<<<512, 256, 0, stream>>>(a_buf, hstart, out);
}